// Round 10
// baseline (1057.750 us; speedup 1.0000x reference)
//
#include <hip/hip_runtime.h>
#include <hip/hip_bf16.h>
#include <cstdint>

#define LH   50
#define PP   30
#define NAG  2048
#define NHID 128
#define EHID 256
#define ADIM 64
#define CNND 2048

typedef __attribute__((ext_vector_type(8))) short bf16x8;
typedef __attribute__((ext_vector_type(4))) float f32x4;

// ---- workspace layout (float slots) -----------------------------------------
// W layout: [c=8][s=4][j=1024][i=8] bf16  (k = c*32 + s*8 + i)
enum : int {
  WS_WT  = 0,        // 131072 fl (512KB)
  WS_WHT = 131072,   // bf16 WhtT[512][128] -> 32768
  WS_WFN = 163840,   // wf0[1024] wf1[1024]
  WS_BFN = 165888,   // wb[1024]
  WS_WFT = 166912,   // 2*512
  WS_BFT = 167936,   // 512
  WS_TH  = 168448,   // 128
  WS_TC  = 168576,   // 128
  WS_W49 = 168704,   // 2048
  WS_CN  = 170752,   // 1 (+3 pad)
  WS_Z   = 170756,   // 30*2048*2
  WS_END = 293636
};

__device__ __forceinline__ float sigf(float x){ return 1.0f/(1.0f + __expf(-x)); }
__device__ __forceinline__ float tanhfast(float x){
  x = fminf(15.0f, fmaxf(-15.0f, x));
  float e = __expf(2.0f*x);
  return (e - 1.0f)/(e + 1.0f);
}
__device__ __forceinline__ float bfs(short s){
  return __uint_as_float(((unsigned)(unsigned short)s) << 16);
}
__device__ __forceinline__ void gld16(const void* g, void* l){
  __builtin_amdgcn_global_load_lds(
      (const __attribute__((address_space(1))) unsigned int*)g,
      (__attribute__((address_space(3))) unsigned int*)l, 16, 0, 0);
}

// ---- prep: WhhT -> [c][s][j][8] bf16, WhtT, folded gate weights --------------
__global__ void k_prep(const float* __restrict__ Whhn, const float* __restrict__ Whht,
                       const float* __restrict__ Wnemb, const float* __restrict__ bnemb,
                       const float* __restrict__ Wihn,  const float* __restrict__ bihn,
                       const float* __restrict__ bhhn,
                       const float* __restrict__ Wtemb, const float* __restrict__ btemb,
                       const float* __restrict__ Wiht,  const float* __restrict__ biht,
                       const float* __restrict__ bhht,
                       float* __restrict__ ws)
{
  const int b = blockIdx.x, tid = threadIdx.x;
  if (b < 256){
    __shared__ float t[32][33];
    __hip_bfloat16* WT = (__hip_bfloat16*)(ws + WS_WT);
    const int tx = tid & 31, ty = tid >> 5;     // ty in [0,8)
    const int j0 = (b & 31) << 5;
    const int c  = b >> 5;                      // 0..7 (k-chunk)
    const int e0 = c << 5;
    #pragma unroll
    for (int r = 0; r < 4; ++r)
      t[ty + 8*r][tx] = Whhn[(e0 + ty + 8*r)*1024 + j0 + tx];
    __syncthreads();
    // element (kk=ty+8r, jj=tx): WT[c*32768 + r*8192 + (j0+tx)*8 + ty]
    #pragma unroll
    for (int r = 0; r < 4; ++r)
      WT[c*32768 + r*8192 + (j0 + tx)*8 + ty] = __float2bfloat16(t[ty + 8*r][tx]);
  } else {
    for (int j = tid; j < 1024; j += 256){
      float a0=0.f, a1=0.f, ab=0.f;
      for (int k=0;k<64;k++){
        const float w = Wihn[k*1024 + j];
        a0 += Wnemb[k]*w; a1 += Wnemb[64+k]*w; ab += bnemb[k]*w;
      }
      ws[WS_WFN + j]        = a0;
      ws[WS_WFN + 1024 + j] = a1;
      ws[WS_BFN + j]        = ab + bihn[j] + bhhn[j];
    }
    for (int j = tid; j < 512; j += 256){
      float a0=0.f, a1=0.f, ab=0.f;
      for (int k=0;k<64;k++){
        const float w = Wiht[k*512 + j];
        a0 += Wtemb[k]*w; a1 += Wtemb[64+k]*w; ab += btemb[k]*w;
      }
      ws[WS_WFT + j]       = a0;
      ws[WS_WFT + 512 + j] = a1;
      ws[WS_BFT + j]       = ab + biht[j] + bhht[j];
    }
    __hip_bfloat16* WTt = (__hip_bfloat16*)(ws + WS_WHT);
    for (int j = tid; j < 512; j += 256)
      for (int k = 0; k < 128; ++k)
        WTt[j*128 + k] = __float2bfloat16(Whht[k*512 + j]);
  }
}

// ---- Phase A ------------------------------------------------------------------
// b<128: 16-agent 78-step chain, 256 threads (4 waves), <=240 VGPR.
//   Wave wv covers tiles (g=0..3, t=0..3): j = g*256 + wv*64 + t*16 + llo.
//   W: chunk0 in regs; chunks 1..7 streamed gld_lds -> 2x64KB LDS ring,
//   counted s_waitcnt vmcnt(16), never drained in-loop.
// b==128: target obs chain.  b==129: w49 precompute.
// dyn LDS: wbuf 131072 | Hl 2x4224 sh (16896) | relS 6400B | vS 2048B | zS 3840B
#define STAGE(cc, bb_) do { \
  const char* gsrc_ = wgl + (cc)*65536 + wv*16384 + lane*16; \
  char* ldst_ = (char*)wbuf + (bb_)*65536 + wv*16384; \
  _Pragma("unroll") \
  for (int q_ = 0; q_ < 16; ++q_) gld16(gsrc_ + q_*1024, ldst_ + q_*1024); \
} while(0)

__global__ __launch_bounds__(256, 1) void k_phaseA(
    const float* __restrict__ nh0, const float* __restrict__ nc0,
    const float* __restrict__ nrel, const int* __restrict__ nhist,
    const float* __restrict__ Wpred,
    const float* __restrict__ trel, const int* __restrict__ thsp,
    const float* __restrict__ Whht, const float* __restrict__ th0,
    const float* __restrict__ tc0,
    const float* __restrict__ tpos, const float* __restrict__ npos,
    const float* __restrict__ Wtatt, const float* __restrict__ btatt,
    const float* __restrict__ Wnatt, const float* __restrict__ bnatt,
    float* __restrict__ ws)
{
  extern __shared__ char smem[];
  const int b = blockIdx.x, tid = threadIdx.x;
  const int wv = tid >> 6, lane = tid & 63;
  const int lhi = lane >> 4, llo = lane & 15;

  if (b < 128){
    short* wbuf = (short*)smem;                    // [2][32768] shorts
    short* Hl   = (short*)(smem + 131072);         // [2][16*264]
    float* relS = (float*)(smem + 147968);         // 1600 fl
    float* vS   = (float*)(smem + 154368);         // 512 fl
    float* zS   = (float*)(smem + 156416);         // 960 fl
    const int n0 = b << 4;
    const short* wt = (const short*)(ws + WS_WT);
    const char*  wgl = (const char*)wt;

    // ---- one-time register state ----
    bf16x8 wreg[4][4];        // chunk 0, [g][t] -> 64 VGPR
    float wfa[4][4], wfb[4][4], wbb[4][4];   // 48 VGPR
    #pragma unroll
    for (int g = 0; g < 4; ++g)
      #pragma unroll
      for (int t = 0; t < 4; ++t){
        const int j = g*256 + (wv<<6) + t*16 + llo;
        wreg[g][t] = *(const bf16x8*)(wt + lhi*8192 + j*8);
        wfa[g][t] = ws[WS_WFN + j];
        wfb[g][t] = ws[WS_WFN + 1024 + j];
        wbb[g][t] = ws[WS_BFN + j];
      }
    float C[4][4];            // 16 VGPR  (r=agent-sub, t=e-slice)
    #pragma unroll
    for (int r = 0; r < 4; ++r)
      #pragma unroll
      for (int t = 0; t < 4; ++t)
        C[r][t] = nc0[(wv<<6) + t*16 + llo];
    int nh4[4];
    #pragma unroll
    for (int r = 0; r < 4; ++r) nh4[r] = nhist[n0 + lhi*4 + r];

    // prologue stream: chunks 1,2
    STAGE(1, 0);
    STAGE(2, 1);

    // shared init
    for (int i = tid; i < 1600; i += 256){
      const int a = i / 100, r = i % 100;
      relS[a*100 + r] = nrel[(n0 + a)*100 + r];
    }
    if (tid < 256){
      vS[2*tid]   = Wpred[2*(NHID + CNND + tid)];
      vS[2*tid+1] = Wpred[2*(NHID + CNND + tid) + 1];
    }
    for (int i = tid; i < 4096; i += 256){
      const int a = i >> 8, e = i & 255;
      ((__hip_bfloat16*)Hl)[a*264 + e] = __float2bfloat16(nh0[e]);
    }
    __syncthreads();

    int cur = 0, ccons = 1, cnext = 3, pb = 0;
    for (int st = 1; st <= 78; ++st){
      const int thr  = (st <= 49) ? (50 - st) : -1;
      const int tsel = (st <= 49) ? st : 49;
      const short* hc = Hl + cur*4224 + llo*264 + lhi*8;

      f32x4 acc[4][4];
      #pragma unroll
      for (int g = 0; g < 4; ++g)
        #pragma unroll
        for (int t = 0; t < 4; ++t) acc[g][t] = (f32x4){0.f,0.f,0.f,0.f};

      // chunk 0 from regs
      {
        const bf16x8 af0 = *(const bf16x8*)(hc);
        #pragma unroll
        for (int g = 0; g < 4; ++g)
          #pragma unroll
          for (int t = 0; t < 4; ++t)
            acc[g][t] = __builtin_amdgcn_mfma_f32_16x16x32_bf16(af0, wreg[g][t], acc[g][t], 0,0,0);
      }
      // chunks 1..7 streamed (ring order)
      for (int p = 0; p < 7; ++p){
        asm volatile("s_waitcnt vmcnt(16)" ::: "memory");   // our loads + next chunk's 16 in flight
        __builtin_amdgcn_sched_barrier(0);
        __builtin_amdgcn_s_barrier();                        // all waves' quarters staged
        __builtin_amdgcn_sched_barrier(0);
        const short* bb = wbuf + pb*32768;
        const bf16x8 afs = *(const bf16x8*)(hc + ccons*32);
        #pragma unroll
        for (int g = 0; g < 4; ++g)
          #pragma unroll
          for (int t = 0; t < 4; ++t){
            const int j = g*256 + (wv<<6) + t*16 + llo;
            const bf16x8 bw = *(const bf16x8*)(bb + lhi*8192 + j*8);
            acc[g][t] = __builtin_amdgcn_mfma_f32_16x16x32_bf16(afs, bw, acc[g][t], 0,0,0);
          }
        asm volatile("s_waitcnt lgkmcnt(0)" ::: "memory");   // own ds_reads landed
        __builtin_amdgcn_sched_barrier(0);
        __builtin_amdgcn_s_barrier();                        // all waves done with this buf
        __builtin_amdgcn_sched_barrier(0);
        STAGE(cnext, pb);                                    // refill freed buf
        ccons = (ccons == 7) ? 1 : ccons + 1;
        cnext = (cnext == 7) ? 1 : cnext + 1;
        pb ^= 1;
      }

      // gates + masked update -> other H buffer
      {
        short* hn = Hl + (cur^1)*4224;
        const short* ho = Hl + cur*4224;
        float2 rr[4];
        #pragma unroll
        for (int r = 0; r < 4; ++r)
          rr[r] = *(const float2*)(relS + (lhi*4 + r)*100 + 2*tsel);
        #pragma unroll
        for (int t = 0; t < 4; ++t){
          const int e = (wv<<6) + t*16 + llo;
          #pragma unroll
          for (int r = 0; r < 4; ++r){
            const int ag = lhi*4 + r;
            const float gi = acc[0][t][r] + rr[r].x*wfa[0][t] + rr[r].y*wfb[0][t] + wbb[0][t];
            const float gf = acc[1][t][r] + rr[r].x*wfa[1][t] + rr[r].y*wfb[1][t] + wbb[1][t];
            const float gg = acc[2][t][r] + rr[r].x*wfa[2][t] + rr[r].y*wfb[2][t] + wbb[2][t];
            const float go = acc[3][t][r] + rr[r].x*wfa[3][t] + rr[r].y*wfb[3][t] + wbb[3][t];
            const float c2 = sigf(gf)*C[r][t] + sigf(gi)*tanhfast(gg);
            const float h2 = sigf(go)*tanhfast(c2);
            const bool mk = nh4[r] > thr;
            if (mk) C[r][t] = c2;
            const short hold = ho[ag*264 + e];
            short hnew; { __hip_bfloat16 hb = __float2bfloat16(h2); hnew = *(short*)&hb; }
            hn[ag*264 + e] = mk ? hnew : hold;
          }
        }
      }
      __syncthreads();      // H[nxt] visible
      cur ^= 1;

      if (st >= 49){
        const int s = st - 49;
        const int a = tid >> 4, sub = tid & 15;
        const short* hp = Hl + cur*4224 + a*264 + sub*16;
        float z0 = 0.f, z1 = 0.f;
        #pragma unroll
        for (int i = 0; i < 16; ++i){
          const float h = bfs(hp[i]);
          z0 += h*vS[2*(sub*16 + i)];
          z1 += h*vS[2*(sub*16 + i) + 1];
        }
        #pragma unroll
        for (int o = 8; o > 0; o >>= 1){
          z0 += __shfl_down(z0, o, 16);
          z1 += __shfl_down(z1, o, 16);
        }
        if (sub == 0){
          zS[s*32 + a*2]     = z0;
          zS[s*32 + a*2 + 1] = z1;
        }
      }
    }
    __syncthreads();
    // dump z buffer
    for (int i = tid; i < 960; i += 256){
      const int s = i >> 5, rem = i & 31;
      ws[WS_Z + (s*NAG + n0 + (rem >> 1))*2 + (rem & 1)] = zS[i];
    }
  }
  else if (b == 128){
    // target obs chain, 256 threads x 2 gate cols
    float* hT = (float*)smem;
    float* cT = hT + 128;
    float* gT = cT + 128;      // 512
    if (tid < 128){ hT[tid] = th0[tid]; cT[tid] = tc0[tid]; }
    __syncthreads();
    const int ths = thsp[0];
    for (int t = 1; t < 50; ++t){
      const float x0 = trel[2*t], x1 = trel[2*t+1];
      #pragma unroll
      for (int q = 0; q < 2; ++q){
        const int j = tid + q*256;
        float acc = x0*ws[WS_WFT + j] + x1*ws[WS_WFT + 512 + j] + ws[WS_BFT + j];
        for (int k = 0; k < 128; ++k) acc += hT[k]*Whht[k*512 + j];
        gT[j] = acc;
      }
      __syncthreads();
      if (tid < 128 && ths > 50 - t){
        const float ig = sigf(gT[tid]),          fg = sigf(gT[128 + tid]);
        const float gg = tanhfast(gT[256 + tid]), og = sigf(gT[384 + tid]);
        const float c2 = fg*cT[tid] + ig*gg;
        cT[tid] = c2; hT[tid] = og*tanhfast(c2);
      }
      __syncthreads();
    }
    if (tid < 128){ ws[WS_TH + tid] = hT[tid]; ws[WS_TC + tid] = cT[tid]; }
  }
  else {
    // w49 precompute, 256 threads
    float* at  = (float*)smem;       // 64
    float* red = at + 64;            // 256
    float* uv  = red + 256;          // 3
    const int t = LH - 1;
    const float tr0 = trel[2*t], tr1 = trel[2*t+1];
    const float tp0 = tpos[2*t], tp1 = tpos[2*t+1];
    if (tid < ADIM) at[tid] = tr0*Wtatt[tid] + tr1*Wtatt[ADIM+tid] + btatt[tid];
    int cnt = 0;
    #pragma unroll
    for (int i = 0; i < 8; ++i) cnt += (nhist[tid + 256*i] > (LH - t)) ? 1 : 0;
    red[tid] = (float)cnt;
    __syncthreads();
    if (tid == 0){
      float u0=0.f,u1=0.f,v=0.f;
      for (int k=0;k<ADIM;k++){ u0 += Wnatt[k]*at[k]; u1 += Wnatt[ADIM+k]*at[k]; v += bnatt[k]*at[k]; }
      uv[0]=u0; uv[1]=u1; uv[2]=v;
    }
    for (int s = 128; s > 0; s >>= 1){ if (tid < s) red[tid] += red[tid+s]; __syncthreads(); }
    const float currN = red[0];
    __syncthreads();
    const float u0 = uv[0], u1 = uv[1], v = uv[2];
    const float scale = currN * 0.125f;
    float sc[8]; float smax = -3.0e38f;
    #pragma unroll
    for (int i = 0; i < 8; ++i){
      const int n = tid + 256*i;
      const float p0 = npos[n*100 + 2*t], p1 = npos[n*100 + 2*t + 1];
      float s = scale * ((tp0-p0)*u0 + (tp1-p1)*u1 + v);
      s = (nhist[n] > (LH - t)) ? s : -1.0e30f;
      sc[i] = s; smax = fmaxf(smax, s);
    }
    red[tid] = smax; __syncthreads();
    for (int s = 128; s > 0; s >>= 1){ if (tid<s) red[tid] = fmaxf(red[tid], red[tid+s]); __syncthreads(); }
    smax = red[0]; __syncthreads();
    float ssum = 0.f;
    #pragma unroll
    for (int i = 0; i < 8; ++i){ sc[i] = __expf(sc[i]-smax); ssum += sc[i]; }
    red[tid] = ssum; __syncthreads();
    for (int s = 128; s > 0; s >>= 1){ if (tid<s) red[tid] += red[tid+s]; __syncthreads(); }
    const float inv = 1.0f / red[0];
    #pragma unroll
    for (int i = 0; i < 8; ++i) ws[WS_W49 + tid + 256*i] = sc[i]*inv;
    if (tid == 0) ws[WS_CN] = currN;
  }
}

// ---- Phase B: all 30 pred steps in one block ---------------------------------
template<int K>
__device__ __forceinline__ void bredN(const float* v, volatile float* scratch,
                                      volatile float* outv, int tid){
  const int lane = tid & 63, wv = tid >> 6;
  #pragma unroll
  for (int k = 0; k < K; ++k){
    float x = v[k];
    #pragma unroll
    for (int o = 32; o > 0; o >>= 1) x += __shfl_down(x, o, 64);
    if (lane == 0) scratch[k*8 + wv] = x;
  }
  __syncthreads();
  if (tid == 0){
    #pragma unroll
    for (int k = 0; k < K; ++k){
      float s = 0.f;
      for (int i = 0; i < 8; ++i) s += scratch[k*8 + i];
      outv[k] = s;
    }
  }
  __syncthreads();
}

__device__ __forceinline__ float bredMax1(float x, volatile float* scratch,
                                          volatile float* outv, int tid){
  const int lane = tid & 63, wv = tid >> 6;
  #pragma unroll
  for (int o = 32; o > 0; o >>= 1) x = fmaxf(x, __shfl_down(x, o, 64));
  if (lane == 0) scratch[wv] = x;
  __syncthreads();
  if (tid == 0){
    float s = -3.0e38f;
    for (int i = 0; i < 8; ++i) s = fmaxf(s, scratch[i]);
    outv[0] = s;
  }
  __syncthreads();
  return outv[0];
}

__global__ __launch_bounds__(512, 1) void k_phaseB(
    const float* __restrict__ img, const float* __restrict__ tpos,
    const float* __restrict__ npos, const float* __restrict__ nh0,
    const float* __restrict__ Wpred, const float* __restrict__ bpred,
    const float* __restrict__ Wtatt, const float* __restrict__ btatt,
    const float* __restrict__ Wnatt, const float* __restrict__ bnatt,
    float* __restrict__ ws, float* __restrict__ out)
{
  __shared__ float p0s[NAG], p1s[NAG];
  __shared__ float th[128], tc[128], gl[512], at[64];
  __shared__ float scratch[24];
  __shared__ float bc[8];
  const int tid = threadIdx.x, lane = tid & 63, wv = tid >> 6;

  bf16x8 wreg[16];
  {
    const short* wp = (const short*)(ws + WS_WHT) + tid*128;
    #pragma unroll
    for (int f = 0; f < 16; ++f) wreg[f] = *(const bf16x8*)(wp + f*8);
  }
  for (int n = tid; n < NAG; n += 512){
    p0s[n] = npos[n*100 + 98];
    p1s[n] = npos[n*100 + 99];
  }
  if (tid < 128){ th[tid] = ws[WS_TH + tid]; tc[tid] = ws[WS_TC + tid]; }

  {
    float v[2] = {0.f, 0.f};
    for (int k = tid; k < CNND; k += 512){
      v[0] += img[k]*Wpred[2*(128 + k)];
      v[1] += img[k]*Wpred[2*(128 + k) + 1];
    }
    bredN<2>(v, scratch, bc, tid);
  }
  const float imgW0 = bc[0], imgW1 = bc[1];
  {
    float v[2] = {0.f, 0.f};
    if (tid < 256){
      v[0] = nh0[tid]*Wpred[2*(128 + CNND + tid)];
      v[1] = nh0[tid]*Wpred[2*(128 + CNND + tid) + 1];
    }
    bredN<2>(v, scratch, bc + 2, tid);
  }
  const float fb0 = bc[2], fb1 = bc[3];
  const float currN = ws[WS_CN];
  float pos0 = tpos[98], pos1 = tpos[99];
  float u0 = 0.f, u1 = 0.f, A = 0.f;
  __syncthreads();

  for (int s = 0; s < PP; ++s){
    const float* zs = ws + WS_Z + s*(NAG*2);
    float hv0, hv1;
    if (s == 0){
      if (currN >= 1.0f){
        float v[2] = {0.f, 0.f};
        for (int n = tid; n < NAG; n += 512){
          const float w = ws[WS_W49 + n];
          v[0] += w*zs[2*n]; v[1] += w*zs[2*n + 1];
        }
        bredN<2>(v, scratch, bc, tid);
        hv0 = bc[0]; hv1 = bc[1];
      } else { hv0 = fb0; hv1 = fb1; }
    } else {
      float sc[4], mx = -3.0e38f;
      #pragma unroll
      for (int i = 0; i < 4; ++i){
        const int n = tid + 512*i;
        sc[i] = 256.0f * (A - (p0s[n]*u0 + p1s[n]*u1));
        mx = fmaxf(mx, sc[i]);
      }
      mx = bredMax1(mx, scratch, bc + 7, tid);
      float v[3] = {0.f, 0.f, 0.f};
      #pragma unroll
      for (int i = 0; i < 4; ++i){
        const int n = tid + 512*i;
        const float e = __expf(sc[i] - mx);
        v[0] += e; v[1] += e*zs[2*n]; v[2] += e*zs[2*n + 1];
      }
      bredN<3>(v, scratch, bc, tid);
      const float inv = 1.0f / bc[0];
      hv0 = bc[1]*inv; hv1 = bc[2]*inv;
    }
    {
      float v[2] = {0.f, 0.f};
      if (tid < 128){
        v[0] = th[tid]*Wpred[2*tid];
        v[1] = th[tid]*Wpred[2*tid + 1];
      }
      bredN<2>(v, scratch, bc + 2, tid);
    }
    const float pr0 = bc[2] + imgW0 + hv0 + bpred[0];
    const float pr1 = bc[3] + imgW1 + hv1 + bpred[1];
    if (tid == 0){ out[2*s] = pr0; out[2*s + 1] = pr1; }
    pos0 += pr0; pos1 += pr1;

    {
      float g = pr0*ws[WS_WFT + tid] + pr1*ws[WS_WFT + 512 + tid] + ws[WS_BFT + tid];
      #pragma unroll
      for (int f = 0; f < 16; ++f){
        #pragma unroll
        for (int i = 0; i < 8; ++i)
          g += bfs(wreg[f][i]) * th[f*8 + i];
      }
      gl[tid] = g;
    }
    __syncthreads();
    float hnew = 0.f, cnew = 0.f;
    if (tid < 128){
      const float ig = sigf(gl[tid]),           fg = sigf(gl[128 + tid]);
      const float gg = tanhfast(gl[256 + tid]), og = sigf(gl[384 + tid]);
      cnew = fg*tc[tid] + ig*gg;
      hnew = og*tanhfast(cnew);
    }
    __syncthreads();
    if (tid < 128){ th[tid] = hnew; tc[tid] = cnew; }

    if (tid < ADIM) at[tid] = pr0*Wtatt[tid] + pr1*Wtatt[ADIM + tid] + btatt[tid];
    __syncthreads();
    if (wv == 0){
      float uu0 = Wnatt[lane]*at[lane];
      float uu1 = Wnatt[ADIM + lane]*at[lane];
      float vv  = bnatt[lane]*at[lane];
      #pragma unroll
      for (int o = 32; o > 0; o >>= 1){
        uu0 += __shfl_down(uu0, o, 64);
        uu1 += __shfl_down(uu1, o, 64);
        vv  += __shfl_down(vv,  o, 64);
      }
      if (lane == 0){
        bc[4] = uu0; bc[5] = uu1;
        bc[6] = pos0*uu0 + pos1*uu1 + vv;
      }
    }
    __syncthreads();
    u0 = bc[4]; u1 = bc[5]; A = bc[6];
  }
}

extern "C" void kernel_launch(void* const* d_in, const int* in_sizes, int n_in,
                              void* d_out, int out_size, void* d_ws, size_t ws_size,
                              hipStream_t stream) {
  const float* img   = (const float*)d_in[0];
  const float* tpos  = (const float*)d_in[1];
  const float* trel  = (const float*)d_in[2];
  const float* npos  = (const float*)d_in[3];
  const float* nrel  = (const float*)d_in[4];
  const int*   nhist = (const int*)d_in[5];
  const int*   ths   = (const int*)d_in[6];
  const float* th0   = (const float*)d_in[7];
  const float* tc0   = (const float*)d_in[8];
  const float* Wtemb = (const float*)d_in[9];
  const float* btemb = (const float*)d_in[10];
  const float* Wiht  = (const float*)d_in[11];
  const float* Whht  = (const float*)d_in[12];
  const float* biht  = (const float*)d_in[13];
  const float* bhht  = (const float*)d_in[14];
  const float* Wtatt = (const float*)d_in[15];
  const float* btatt = (const float*)d_in[16];
  const float* nh0   = (const float*)d_in[17];
  const float* nc0   = (const float*)d_in[18];
  const float* Wnemb = (const float*)d_in[19];
  const float* bnemb = (const float*)d_in[20];
  const float* Wihn  = (const float*)d_in[21];
  const float* Whhn  = (const float*)d_in[22];
  const float* bihn  = (const float*)d_in[23];
  const float* bhhn  = (const float*)d_in[24];
  const float* Wnatt = (const float*)d_in[25];
  const float* bnatt = (const float*)d_in[26];
  const float* Wpred = (const float*)d_in[27];
  const float* bpred = (const float*)d_in[28];
  float* ws  = (float*)d_ws;
  float* out = (float*)d_out;

  const int ldsA = 160256;

  k_prep<<<257, 256, 0, stream>>>(Whhn, Whht, Wnemb, bnemb, Wihn, bihn, bhhn,
                                  Wtemb, btemb, Wiht, biht, bhht, ws);
  k_phaseA<<<130, 256, ldsA, stream>>>(nh0, nc0, nrel, nhist, Wpred,
                                       trel, ths, Whht, th0, tc0,
                                       tpos, npos, Wtatt, btatt, Wnatt, bnatt, ws);
  k_phaseB<<<1, 512, 0, stream>>>(img, tpos, npos, nh0, Wpred, bpred,
                                  Wtatt, btatt, Wnatt, bnatt, ws, out);
}